// Round 1
// baseline (6456.076 us; speedup 1.0000x reference)
//
#include <hip/hip_runtime.h>
#include <hip/hip_bf16.h>

#define DIMK 1024
#define SEQ  2048
#define BATCH 4
#define NTOK (BATCH*SEQ)           // 8192
#define PROJ_ELEMS (NTOK*DIMK)     // 8388608 per buffer

__device__ __forceinline__ float bf2f(unsigned short u) {
    union { unsigned int i; float f; } x;
    x.i = ((unsigned int)u) << 16;
    return x.f;
}

// ---------------------------------------------------------------------------
// Kernel 1: complex projection  Yr = Zr@Wr^T - Zi@Wi^T ; Yi = Zi@Wr^T + Zr@Wi^T
// Z: [8192,1024] fp32 row-major, W: [1024,1024] fp32 row-major ([out,in]).
// NT GEMM: C[m,n] = sum_k Z[m,k]*W[n,k]. Outputs bf16.
// grid (N/64, M/64), block (16,16); 64x64x16 tiles, 4x4 per thread.
// ---------------------------------------------------------------------------
__global__ __launch_bounds__(256)
void proj_kernel(const float* __restrict__ zr, const float* __restrict__ zi,
                 const float* __restrict__ wr, const float* __restrict__ wi,
                 __hip_bfloat16* __restrict__ yr, __hip_bfloat16* __restrict__ yi)
{
    __shared__ float Zr[64][17], Zi[64][17], Wr[64][17], Wi[64][17];
    const int tid = threadIdx.y * 16 + threadIdx.x;
    const int lr  = tid >> 2;         // 0..63
    const int lc  = (tid & 3) * 4;    // 0,4,8,12
    const int m0  = blockIdx.y * 64;
    const int n0  = blockIdx.x * 64;

    float accr[4][4] = {{0.f}}, acci[4][4] = {{0.f}};

    const size_t zrow = (size_t)(m0 + lr) * DIMK;
    const size_t wrow = (size_t)(n0 + lr) * DIMK;

    for (int k0 = 0; k0 < DIMK; k0 += 16) {
        float4 a = *(const float4*)&zr[zrow + k0 + lc];
        float4 b = *(const float4*)&zi[zrow + k0 + lc];
        float4 c = *(const float4*)&wr[wrow + k0 + lc];
        float4 d = *(const float4*)&wi[wrow + k0 + lc];
        Zr[lr][lc+0]=a.x; Zr[lr][lc+1]=a.y; Zr[lr][lc+2]=a.z; Zr[lr][lc+3]=a.w;
        Zi[lr][lc+0]=b.x; Zi[lr][lc+1]=b.y; Zi[lr][lc+2]=b.z; Zi[lr][lc+3]=b.w;
        Wr[lr][lc+0]=c.x; Wr[lr][lc+1]=c.y; Wr[lr][lc+2]=c.z; Wr[lr][lc+3]=c.w;
        Wi[lr][lc+0]=d.x; Wi[lr][lc+1]=d.y; Wi[lr][lc+2]=d.z; Wi[lr][lc+3]=d.w;
        __syncthreads();
        #pragma unroll
        for (int kk = 0; kk < 16; ++kk) {
            float zrf[4], zif[4], wrf[4], wif[4];
            #pragma unroll
            for (int i = 0; i < 4; ++i) {
                zrf[i] = Zr[threadIdx.y*4+i][kk];
                zif[i] = Zi[threadIdx.y*4+i][kk];
            }
            #pragma unroll
            for (int j = 0; j < 4; ++j) {
                wrf[j] = Wr[threadIdx.x*4+j][kk];
                wif[j] = Wi[threadIdx.x*4+j][kk];
            }
            #pragma unroll
            for (int i = 0; i < 4; ++i)
                #pragma unroll
                for (int j = 0; j < 4; ++j) {
                    accr[i][j] += zrf[i]*wrf[j] - zif[i]*wif[j];
                    acci[i][j] += zif[i]*wrf[j] + zrf[i]*wif[j];
                }
        }
        __syncthreads();
    }

    #pragma unroll
    for (int i = 0; i < 4; ++i) {
        const size_t m = (size_t)(m0 + threadIdx.y*4 + i);
        #pragma unroll
        for (int j = 0; j < 4; ++j) {
            const size_t n = (size_t)(n0 + threadIdx.x*4 + j);
            yr[m*DIMK + n] = __float2bfloat16(accr[i][j]);
            yi[m*DIMK + n] = __float2bfloat16(acci[i][j]);
        }
    }
}

// ---------------------------------------------------------------------------
// Kernel 2: scores[b,s,t] = (qr.kr + qi.ki) * 1/32 for block tiles with t<=s
// reachable. Tiles fully above the diagonal are skipped (never read later).
// grid (32 t-tiles, 32 s-tiles, 4 batches), block (16,16).
// ---------------------------------------------------------------------------
__global__ __launch_bounds__(256)
void scores_kernel(const __hip_bfloat16* __restrict__ q_r, const __hip_bfloat16* __restrict__ q_i,
                   const __hip_bfloat16* __restrict__ k_r, const __hip_bfloat16* __restrict__ k_i,
                   float* __restrict__ sc)
{
    const int jt = blockIdx.x;   // t tile
    const int it = blockIdx.y;   // s tile
    if (jt > it) return;         // fully masked tile -> never read
    const int b = blockIdx.z;

    __shared__ float Qr[64][17], Qi[64][17], Kr[64][17], Ki[64][17];
    const int tid = threadIdx.y * 16 + threadIdx.x;
    const int lr  = tid >> 2;
    const int lc  = (tid & 3) * 4;
    const int s0  = it * 64, t0 = jt * 64;

    const unsigned short* qru = (const unsigned short*)q_r;
    const unsigned short* qiu = (const unsigned short*)q_i;
    const unsigned short* kru = (const unsigned short*)k_r;
    const unsigned short* kiu = (const unsigned short*)k_i;

    const size_t qrow = ((size_t)b*SEQ + s0 + lr) * DIMK;
    const size_t krow = ((size_t)b*SEQ + t0 + lr) * DIMK;

    float acc[4][4] = {{0.f}};

    for (int k0 = 0; k0 < DIMK; k0 += 16) {
        ushort4 a = *(const ushort4*)&qru[qrow + k0 + lc];
        ushort4 bq = *(const ushort4*)&qiu[qrow + k0 + lc];
        ushort4 c = *(const ushort4*)&kru[krow + k0 + lc];
        ushort4 d = *(const ushort4*)&kiu[krow + k0 + lc];
        Qr[lr][lc+0]=bf2f(a.x);  Qr[lr][lc+1]=bf2f(a.y);  Qr[lr][lc+2]=bf2f(a.z);  Qr[lr][lc+3]=bf2f(a.w);
        Qi[lr][lc+0]=bf2f(bq.x); Qi[lr][lc+1]=bf2f(bq.y); Qi[lr][lc+2]=bf2f(bq.z); Qi[lr][lc+3]=bf2f(bq.w);
        Kr[lr][lc+0]=bf2f(c.x);  Kr[lr][lc+1]=bf2f(c.y);  Kr[lr][lc+2]=bf2f(c.z);  Kr[lr][lc+3]=bf2f(c.w);
        Ki[lr][lc+0]=bf2f(d.x);  Ki[lr][lc+1]=bf2f(d.y);  Ki[lr][lc+2]=bf2f(d.z);  Ki[lr][lc+3]=bf2f(d.w);
        __syncthreads();
        #pragma unroll
        for (int kk = 0; kk < 16; ++kk) {
            float qrf[4], qif[4], krf[4], kif[4];
            #pragma unroll
            for (int i = 0; i < 4; ++i) {
                qrf[i] = Qr[threadIdx.y*4+i][kk];
                qif[i] = Qi[threadIdx.y*4+i][kk];
            }
            #pragma unroll
            for (int j = 0; j < 4; ++j) {
                krf[j] = Kr[threadIdx.x*4+j][kk];
                kif[j] = Ki[threadIdx.x*4+j][kk];
            }
            #pragma unroll
            for (int i = 0; i < 4; ++i)
                #pragma unroll
                for (int j = 0; j < 4; ++j)
                    acc[i][j] += qrf[i]*krf[j] + qif[i]*kif[j];
        }
        __syncthreads();
    }

    const float scale = 0.03125f;   // 1024^-0.5
    #pragma unroll
    for (int i = 0; i < 4; ++i) {
        const size_t row = ((size_t)b*SEQ + s0 + threadIdx.y*4 + i) * SEQ;
        #pragma unroll
        for (int j = 0; j < 4; ++j)
            sc[row + t0 + threadIdx.x*4 + j] = acc[i][j] * scale;
    }
}

// ---------------------------------------------------------------------------
// Kernel 3: causal row softmax, in place. One 256-thread block per row.
// Reads cols [0,s], writes P over [0, round_up(s+1,64)) with zero padding so
// the PV kernel can consume whole 64-wide K tiles.
// ---------------------------------------------------------------------------
__global__ __launch_bounds__(256)
void softmax_kernel(float* __restrict__ sc)
{
    const int row = blockIdx.x;            // 0..8191  (b*SEQ + s)
    const int s   = row & (SEQ - 1);
    float* x = sc + (size_t)row * SEQ;
    const int n = s + 1;
    const int tid  = threadIdx.x;
    const int wave = tid >> 6, lane = tid & 63;
    __shared__ float redm[4], reds[4];

    float m = -1e30f;
    for (int i = tid; i < n; i += 256) m = fmaxf(m, x[i]);
    #pragma unroll
    for (int off = 32; off > 0; off >>= 1) m = fmaxf(m, __shfl_down(m, off, 64));
    if (lane == 0) redm[wave] = m;
    __syncthreads();
    if (tid == 0) redm[0] = fmaxf(fmaxf(redm[0], redm[1]), fmaxf(redm[2], redm[3]));
    __syncthreads();
    m = redm[0];

    float l = 0.f;
    for (int i = tid; i < n; i += 256) l += __expf(x[i] - m);
    #pragma unroll
    for (int off = 32; off > 0; off >>= 1) l += __shfl_down(l, off, 64);
    if (lane == 0) reds[wave] = l;
    __syncthreads();
    if (tid == 0) reds[0] = reds[0] + reds[1] + reds[2] + reds[3];
    __syncthreads();
    const float inv = 1.0f / reds[0];

    const int npad = min(SEQ, (s/64 + 1) * 64);
    for (int i = tid; i < npad; i += 256) {
        float v = (i < n) ? __expf(x[i] - m) * inv : 0.f;
        x[i] = v;
    }
}

// ---------------------------------------------------------------------------
// Kernel 4: out_r = P @ Vr, out_i = P @ Vi  (NN GEMM, causal K extent)
// grid (D/64, SEQ/64, B), block (16,16). K runs over t in [0, (s_tile+1)*64).
// ---------------------------------------------------------------------------
__global__ __launch_bounds__(256)
void pv_kernel(const float* __restrict__ p, const __hip_bfloat16* __restrict__ v_r,
               const __hip_bfloat16* __restrict__ v_i, float* __restrict__ out)
{
    const int b  = blockIdx.z;
    const int st = blockIdx.y;   // s tile 0..31
    const int dt = blockIdx.x;   // d tile 0..15

    __shared__ float Ps[64][17], Vr[16][65], Vi[16][65];

    const int tid = threadIdx.y * 16 + threadIdx.x;
    // P tile load mapping: 64 rows x 16 cols
    const int plr = tid >> 2, plc = (tid & 3) * 4;
    // V tile load mapping: 16 rows x 64 cols
    const int vlr = tid >> 4, vlc = (tid & 15) * 4;

    const int s0 = st * 64, d0 = dt * 64;
    const int kmax = (st + 1) * 64;

    const unsigned short* vru = (const unsigned short*)v_r;
    const unsigned short* viu = (const unsigned short*)v_i;

    float accr[4][4] = {{0.f}}, acci[4][4] = {{0.f}};

    for (int k0 = 0; k0 < kmax; k0 += 16) {
        float4 pa = *(const float4*)&p[((size_t)b*SEQ + s0 + plr) * SEQ + k0 + plc];
        Ps[plr][plc+0]=pa.x; Ps[plr][plc+1]=pa.y; Ps[plr][plc+2]=pa.z; Ps[plr][plc+3]=pa.w;
        ushort4 va = *(const ushort4*)&vru[((size_t)b*SEQ + k0 + vlr) * DIMK + d0 + vlc];
        ushort4 vb = *(const ushort4*)&viu[((size_t)b*SEQ + k0 + vlr) * DIMK + d0 + vlc];
        Vr[vlr][vlc+0]=bf2f(va.x); Vr[vlr][vlc+1]=bf2f(va.y); Vr[vlr][vlc+2]=bf2f(va.z); Vr[vlr][vlc+3]=bf2f(va.w);
        Vi[vlr][vlc+0]=bf2f(vb.x); Vi[vlr][vlc+1]=bf2f(vb.y); Vi[vlr][vlc+2]=bf2f(vb.z); Vi[vlr][vlc+3]=bf2f(vb.w);
        __syncthreads();
        #pragma unroll
        for (int kk = 0; kk < 16; ++kk) {
            float pf[4], vrf[4], vif[4];
            #pragma unroll
            for (int i = 0; i < 4; ++i) pf[i] = Ps[threadIdx.y*4+i][kk];
            #pragma unroll
            for (int j = 0; j < 4; ++j) {
                vrf[j] = Vr[kk][threadIdx.x*4+j];
                vif[j] = Vi[kk][threadIdx.x*4+j];
            }
            #pragma unroll
            for (int i = 0; i < 4; ++i)
                #pragma unroll
                for (int j = 0; j < 4; ++j) {
                    accr[i][j] += pf[i]*vrf[j];
                    acci[i][j] += pf[i]*vif[j];
                }
        }
        __syncthreads();
    }

    float* out_r = out;
    float* out_i = out + (size_t)PROJ_ELEMS;
    #pragma unroll
    for (int i = 0; i < 4; ++i) {
        const size_t o = ((size_t)b*SEQ + s0 + threadIdx.y*4 + i) * DIMK + d0 + threadIdx.x*4;
        float4 r4 = make_float4(accr[i][0], accr[i][1], accr[i][2], accr[i][3]);
        float4 i4 = make_float4(acci[i][0], acci[i][1], acci[i][2], acci[i][3]);
        *(float4*)&out_r[o] = r4;
        *(float4*)&out_i[o] = i4;
    }
}

// ---------------------------------------------------------------------------
extern "C" void kernel_launch(void* const* d_in, const int* in_sizes, int n_in,
                              void* d_out, int out_size, void* d_ws, size_t ws_size,
                              hipStream_t stream)
{
    const float* z_real = (const float*)d_in[0];
    const float* z_imag = (const float*)d_in[1];
    const float* wq_r   = (const float*)d_in[2];
    const float* wq_i   = (const float*)d_in[3];
    const float* wk_r   = (const float*)d_in[4];
    const float* wk_i   = (const float*)d_in[5];
    const float* wv_r   = (const float*)d_in[6];
    const float* wv_i   = (const float*)d_in[7];
    // d_in[8] = mask: known-causal tril, handled analytically.

    // workspace layout: 6 bf16 projection buffers then fp32 scores. 160 MiB.
    __hip_bfloat16* qr = (__hip_bfloat16*)d_ws;
    __hip_bfloat16* qi = qr + PROJ_ELEMS;
    __hip_bfloat16* kr = qi + PROJ_ELEMS;
    __hip_bfloat16* ki = kr + PROJ_ELEMS;
    __hip_bfloat16* vr = ki + PROJ_ELEMS;
    __hip_bfloat16* vi = vr + PROJ_ELEMS;
    float* scores = (float*)(vi + PROJ_ELEMS);

    float* outp = (float*)d_out;

    dim3 blk(16, 16);
    proj_kernel<<<dim3(DIMK/64, NTOK/64), blk, 0, stream>>>(z_real, z_imag, wq_r, wq_i, qr, qi);
    proj_kernel<<<dim3(DIMK/64, NTOK/64), blk, 0, stream>>>(z_real, z_imag, wk_r, wk_i, kr, ki);
    proj_kernel<<<dim3(DIMK/64, NTOK/64), blk, 0, stream>>>(z_real, z_imag, wv_r, wv_i, vr, vi);

    scores_kernel<<<dim3(SEQ/64, SEQ/64, BATCH), blk, 0, stream>>>(qr, qi, kr, ki, scores);
    softmax_kernel<<<dim3(NTOK), dim3(256), 0, stream>>>(scores);
    pv_kernel<<<dim3(DIMK/64, SEQ/64, BATCH), blk, 0, stream>>>(scores, vr, vi, outp);
}

// Round 2
// 643.275 us; speedup vs baseline: 10.0363x; 10.0363x over previous
//
#include <hip/hip_runtime.h>
#include <hip/hip_bf16.h>
#include <hip/hip_fp16.h>

#define DIMK 1024
#define SEQ  2048
#define BATCH 4
#define NTOK (BATCH*SEQ)                    // 8192
#define PROJ_ELEMS ((size_t)NTOK*DIMK)      // 8388608
#define LD 2048                             // leading dim (elements) of every GEMM operand

typedef unsigned short ushort_t;
typedef __attribute__((ext_vector_type(8))) short short8;   // 8 x bf16 (4 VGPRs)
typedef __attribute__((ext_vector_type(4))) float float4v;  // MFMA accumulator

__device__ __forceinline__ unsigned short f2bf(float f) {
    union { float f; unsigned int i; } x; x.f = f;
    unsigned int r = x.i + 0x7fffu + ((x.i >> 16) & 1u);    // RNE
    return (unsigned short)(r >> 16);
}
__device__ __forceinline__ float bf2f(unsigned short u) {
    union { unsigned int i; float f; } x; x.i = ((unsigned int)u) << 16;
    return x.f;
}

// global -> LDS direct copy, 16 B per lane. LDS dest must be wave-uniform;
// HW scatters lane i to base + i*16.
__device__ __forceinline__ void gld_lds16(const void* g, void* l) {
    auto gp = reinterpret_cast<const __attribute__((address_space(1))) unsigned int*>(
        reinterpret_cast<uintptr_t>(g));
    auto lp = reinterpret_cast<__attribute__((address_space(3))) unsigned int*>(
        reinterpret_cast<uintptr_t>(l));
    __builtin_amdgcn_global_load_lds(gp, lp, 16, 0, 0);
}

// ---------------------------------------------------------------------------
// Shared MFMA core: C(128x128) += A(128xK) * B(128xK)^T, both row-major bf16
// with leading dim LD=2048. Block = 256 threads = 4 waves (2x2 of 64x64).
// Per k-step(32): stage A/B tiles via global_load_lds(16B), 8 ds_read_b128,
// 16 mfma_f32_16x16x32_bf16 per wave.
// ---------------------------------------------------------------------------
__device__ __forceinline__ void gemm_core(
    const ushort_t* __restrict__ Arow,   // A + m0*LD
    const ushort_t* __restrict__ Brow,   // B + n0*LD
    int kbeg, int kend,
    ushort_t* Asm, ushort_t* Bsm,        // LDS, 128*32 bf16 each
    float4v acc[4][4], int wave, int lane)
{
    const int srow  = lane >> 2;         // 0..15 (staging row within 16-row chunk)
    const int scol  = (lane & 3) * 8;    // staging col (elements)
    const int col16 = lane & 15;
    const int quad  = lane >> 4;
    const int wm = (wave >> 1) * 64;
    const int wn = (wave & 1) * 64;

    for (int k0 = kbeg; k0 < kend; k0 += 32) {
        #pragma unroll
        for (int inst = 0; inst < 2; ++inst) {
            const int r = (wave * 2 + inst) * 16 + srow;
            gld_lds16(Arow + (size_t)r * LD + k0 + scol, Asm + (wave * 2 + inst) * 512);
            gld_lds16(Brow + (size_t)r * LD + k0 + scol, Bsm + (wave * 2 + inst) * 512);
        }
        __syncthreads();
        short8 af[4], bfr[4];
        #pragma unroll
        for (int i = 0; i < 4; ++i)
            af[i] = *(const short8*)(Asm + (wm + i * 16 + col16) * 32 + quad * 8);
        #pragma unroll
        for (int j = 0; j < 4; ++j)
            bfr[j] = *(const short8*)(Bsm + (wn + j * 16 + col16) * 32 + quad * 8);
        #pragma unroll
        for (int i = 0; i < 4; ++i)
            #pragma unroll
            for (int j = 0; j < 4; ++j)
                acc[i][j] = __builtin_amdgcn_mfma_f32_16x16x32_bf16(af[i], bfr[j], acc[i][j], 0, 0, 0);
        __syncthreads();
    }
}

// ---------------------------------------------------------------------------
// Projection GEMM: C[8192,2048] bf16 = Zcat[8192,2048] @ Wstack[2048,2048]^T
// grid (N/128=16, M/128=64)
// ---------------------------------------------------------------------------
__global__ __launch_bounds__(256)
void gemm_proj(const ushort_t* __restrict__ A, const ushort_t* __restrict__ B,
               ushort_t* __restrict__ C)
{
    __shared__ ushort_t Asm[128 * 32], Bsm[128 * 32];
    const int tid = threadIdx.x, wave = tid >> 6, lane = tid & 63;
    const int m0 = blockIdx.y * 128, n0 = blockIdx.x * 128;
    float4v acc[4][4] = {};
    gemm_core(A + (size_t)m0 * LD, B + (size_t)n0 * LD, 0, 2048, Asm, Bsm, acc, wave, lane);

    const int wm = (wave >> 1) * 64, wn = (wave & 1) * 64;
    const int col16 = lane & 15, quad = lane >> 4;
    #pragma unroll
    for (int i = 0; i < 4; ++i)
        #pragma unroll
        for (int j = 0; j < 4; ++j) {
            const int n = n0 + wn + j * 16 + col16;
            #pragma unroll
            for (int r = 0; r < 4; ++r) {
                const int m = m0 + wm + i * 16 + quad * 4 + r;
                C[(size_t)m * LD + n] = f2bf(acc[i][j][r]);
            }
        }
}

// ---------------------------------------------------------------------------
// Scores GEMM (causal tiles): S[b][s][t] fp16 = (Qcat@Kcat^T)*scale
// grid (16 t-tiles, 16 s-tiles, 4 batches); skip jt>it.
// ---------------------------------------------------------------------------
__global__ __launch_bounds__(256)
void gemm_scores(const ushort_t* __restrict__ Q, const ushort_t* __restrict__ K,
                 __half* __restrict__ S)
{
    const int jt = blockIdx.x, it = blockIdx.y, b = blockIdx.z;
    if (jt > it) return;
    __shared__ ushort_t Asm[128 * 32], Bsm[128 * 32];
    const int tid = threadIdx.x, wave = tid >> 6, lane = tid & 63;
    const size_t boff = (size_t)b * SEQ * LD;
    float4v acc[4][4] = {};
    gemm_core(Q + boff + (size_t)it * 128 * LD, K + boff + (size_t)jt * 128 * LD,
              0, 2048, Asm, Bsm, acc, wave, lane);

    const int wm = (wave >> 1) * 64, wn = (wave & 1) * 64;
    const int col16 = lane & 15, quad = lane >> 4;
    const float scale = 0.03125f;  // 1024^-0.5
    __half* Sb = S + (size_t)b * SEQ * SEQ;
    #pragma unroll
    for (int i = 0; i < 4; ++i)
        #pragma unroll
        for (int j = 0; j < 4; ++j) {
            const int t = jt * 128 + wn + j * 16 + col16;
            #pragma unroll
            for (int r = 0; r < 4; ++r) {
                const int s = it * 128 + wm + i * 16 + quad * 4 + r;
                Sb[(size_t)s * SEQ + t] = __float2half(acc[i][j][r] * scale);
            }
        }
}

// ---------------------------------------------------------------------------
// PV GEMM: out[{r,i}][b][s][d] fp32 = P[b] @ VTstack[b]^T, K extent causal.
// grid (16 n-tiles, 16 s-tiles, 4 batches). n<1024 -> real, else imag.
// ---------------------------------------------------------------------------
__global__ __launch_bounds__(256)
void gemm_pv(const ushort_t* __restrict__ P, const ushort_t* __restrict__ VT,
             float* __restrict__ out)
{
    const int nt = blockIdx.x, mt = blockIdx.y, b = blockIdx.z;
    __shared__ ushort_t Asm[128 * 32], Bsm[128 * 32];
    const int tid = threadIdx.x, wave = tid >> 6, lane = tid & 63;
    const int kend = (mt + 1) * 128;
    float4v acc[4][4] = {};
    gemm_core(P + (size_t)b * SEQ * SEQ + (size_t)mt * 128 * LD,
              VT + (size_t)b * LD * LD + (size_t)nt * 128 * LD,
              0, kend, Asm, Bsm, acc, wave, lane);

    const int wm = (wave >> 1) * 64, wn = (wave & 1) * 64;
    const int col16 = lane & 15, quad = lane >> 4;
    #pragma unroll
    for (int i = 0; i < 4; ++i)
        #pragma unroll
        for (int j = 0; j < 4; ++j) {
            const int n = nt * 128 + wn + j * 16 + col16;
            float* dst = out + ((n < 1024) ? 0 : PROJ_ELEMS);
            const int d = n & 1023;
            #pragma unroll
            for (int r = 0; r < 4; ++r) {
                const int s = mt * 128 + wm + i * 16 + quad * 4 + r;
                dst[((size_t)b * SEQ + s) * DIMK + d] = acc[i][j][r];
            }
        }
}

// ---------------------------------------------------------------------------
// Input converts
// ---------------------------------------------------------------------------
__global__ __launch_bounds__(256)
void zcat_kernel(const float* __restrict__ zr, const float* __restrict__ zi,
                 ushort_t* __restrict__ zcat)
{
    const size_t e = ((size_t)blockIdx.x * 256 + threadIdx.x) * 8;
    const size_t tok = e >> 11;
    const int c = (int)(e & 2047);
    const float* src = (c < 1024) ? (zr + tok * 1024 + c) : (zi + tok * 1024 + (c - 1024));
    float4 a = *(const float4*)src;
    float4 b = *(const float4*)(src + 4);
    ushort_t* d = zcat + e;
    d[0]=f2bf(a.x); d[1]=f2bf(a.y); d[2]=f2bf(a.z); d[3]=f2bf(a.w);
    d[4]=f2bf(b.x); d[5]=f2bf(b.y); d[6]=f2bf(b.z); d[7]=f2bf(b.w);
}

// Wstack[n][c]: n<1024: [wr[n] | -wi[n]] ; n>=1024: [wi[n-1024] | wr[n-1024]]
__global__ __launch_bounds__(256)
void wstack_kernel(const float* __restrict__ wr, const float* __restrict__ wi,
                   ushort_t* __restrict__ ws)
{
    const size_t e = ((size_t)blockIdx.x * 256 + threadIdx.x) * 8;
    const int n = (int)(e >> 11), c = (int)(e & 2047);
    const int n1 = n & 1023, c1 = c & 1023;
    const float* src;
    float sgn = 1.f;
    if (n < 1024) {
        if (c < 1024) src = wr + (size_t)n1 * 1024 + c1;
        else        { src = wi + (size_t)n1 * 1024 + c1; sgn = -1.f; }
    } else {
        src = ((c < 1024) ? wi : wr) + (size_t)n1 * 1024 + c1;
    }
    float4 a = *(const float4*)src;
    float4 b = *(const float4*)(src + 4);
    ushort_t* d = ws + e;
    d[0]=f2bf(sgn*a.x); d[1]=f2bf(sgn*a.y); d[2]=f2bf(sgn*a.z); d[3]=f2bf(sgn*a.w);
    d[4]=f2bf(sgn*b.x); d[5]=f2bf(sgn*b.y); d[6]=f2bf(sgn*b.z); d[7]=f2bf(sgn*b.w);
}

// ---------------------------------------------------------------------------
// V transpose per batch: VT[b][c][t] = Vcat[b*SEQ + t][c], 64x64 LDS tiles.
// grid (32 t-tiles, 32 c-tiles, 4 batches)
// ---------------------------------------------------------------------------
__global__ __launch_bounds__(256)
void transpose_v(const ushort_t* __restrict__ vcat, ushort_t* __restrict__ vt)
{
    __shared__ ushort_t tile[64][65];
    const int b = blockIdx.z;
    const int t0 = blockIdx.x * 64, c0 = blockIdx.y * 64;
    const int tid = threadIdx.x;
    const int r = tid >> 4, c4 = (tid & 15) * 4;
    const ushort_t* src = vcat + ((size_t)(b * SEQ + t0)) * LD + c0;
    #pragma unroll
    for (int p = 0; p < 4; ++p) {
        const int row = p * 16 + r;
        ushort4 v = *(const ushort4*)(src + (size_t)row * LD + c4);
        tile[row][c4+0]=v.x; tile[row][c4+1]=v.y; tile[row][c4+2]=v.z; tile[row][c4+3]=v.w;
    }
    __syncthreads();
    ushort_t* dst = vt + ((size_t)b * LD + c0) * LD + t0;
    #pragma unroll
    for (int p = 0; p < 4; ++p) {
        const int crow = p * 16 + r;
        ushort4 v;
        v.x = tile[c4+0][crow]; v.y = tile[c4+1][crow];
        v.z = tile[c4+2][crow]; v.w = tile[c4+3][crow];
        *(ushort4*)(dst + (size_t)crow * LD + c4) = v;
    }
}

// ---------------------------------------------------------------------------
// Causal softmax: read fp16 scores row [0,s], write bf16 P in place,
// zero-padded to a 128 multiple so PV consumes whole K tiles.
// ---------------------------------------------------------------------------
__global__ __launch_bounds__(256)
void softmax_kernel(__half* __restrict__ sc)
{
    const int row = blockIdx.x;          // b*SEQ + s
    const int s = row & (SEQ - 1);
    __half* x = sc + (size_t)row * SEQ;
    ushort_t* xo = (ushort_t*)x;
    const int n = s + 1;
    const int tid = threadIdx.x, wave = tid >> 6, lane = tid & 63;
    __shared__ float redm[4], reds[4];

    float m = -1e30f;
    for (int i = tid; i < n; i += 256) m = fmaxf(m, __half2float(x[i]));
    #pragma unroll
    for (int off = 32; off > 0; off >>= 1) m = fmaxf(m, __shfl_down(m, off, 64));
    if (lane == 0) redm[wave] = m;
    __syncthreads();
    if (tid == 0) redm[0] = fmaxf(fmaxf(redm[0], redm[1]), fmaxf(redm[2], redm[3]));
    __syncthreads();
    m = redm[0];

    float l = 0.f;
    for (int i = tid; i < n; i += 256) l += __expf(__half2float(x[i]) - m);
    #pragma unroll
    for (int off = 32; off > 0; off >>= 1) l += __shfl_down(l, off, 64);
    if (lane == 0) reds[wave] = l;
    __syncthreads();
    if (tid == 0) reds[0] = reds[0] + reds[1] + reds[2] + reds[3];
    __syncthreads();
    const float inv = 1.0f / reds[0];

    const int npad = min(SEQ, ((s >> 7) + 1) << 7);
    for (int i = tid; i < npad; i += 256) {
        float v = (i < n) ? __expf(__half2float(x[i]) - m) * inv : 0.f;
        xo[i] = f2bf(v);
    }
}

// ---------------------------------------------------------------------------
extern "C" void kernel_launch(void* const* d_in, const int* in_sizes, int n_in,
                              void* d_out, int out_size, void* d_ws, size_t ws_size,
                              hipStream_t stream)
{
    const float* z_real = (const float*)d_in[0];
    const float* z_imag = (const float*)d_in[1];
    const float* wq_r   = (const float*)d_in[2];
    const float* wq_i   = (const float*)d_in[3];
    const float* wk_r   = (const float*)d_in[4];
    const float* wk_i   = (const float*)d_in[5];
    const float* wv_r   = (const float*)d_in[6];
    const float* wv_i   = (const float*)d_in[7];
    // d_in[8]: causal tril mask, handled analytically.

    // Workspace layout (bytes), lifetimes are disjoint by stream order:
    //   [0,          33554432)  Zcat bf16     -> reused as VT bf16
    //   [33554432,   58720256)  Wstack q/k/v bf16 (3 x 8 MiB)
    //   [58720256,   92274688)  Qcat bf16
    //   [92274688,  125829120)  Kcat bf16
    //   [125829120, 159383552)  Vcat bf16     -> reused as scores fp16 / P bf16
    uint8_t* ws = (uint8_t*)d_ws;
    ushort_t* zcat = (ushort_t*)(ws + 0);
    ushort_t* wsq  = (ushort_t*)(ws + 33554432);
    ushort_t* wsk  = (ushort_t*)(ws + 33554432 + 8388608);
    ushort_t* wsv  = (ushort_t*)(ws + 33554432 + 16777216);
    ushort_t* qcat = (ushort_t*)(ws + 58720256);
    ushort_t* kcat = (ushort_t*)(ws + 92274688);
    ushort_t* vcat = (ushort_t*)(ws + 125829120);
    ushort_t* vt   = (ushort_t*)(ws + 0);
    __half*   sc   = (__half*)(ws + 125829120);
    float*    outp = (float*)d_out;

    zcat_kernel<<<dim3(8192), dim3(256), 0, stream>>>(z_real, z_imag, zcat);
    wstack_kernel<<<dim3(2048), dim3(256), 0, stream>>>(wq_r, wq_i, wsq);
    wstack_kernel<<<dim3(2048), dim3(256), 0, stream>>>(wk_r, wk_i, wsk);
    wstack_kernel<<<dim3(2048), dim3(256), 0, stream>>>(wv_r, wv_i, wsv);

    gemm_proj<<<dim3(16, 64), dim3(256), 0, stream>>>(zcat, wsq, qcat);
    gemm_proj<<<dim3(16, 64), dim3(256), 0, stream>>>(zcat, wsk, kcat);
    gemm_proj<<<dim3(16, 64), dim3(256), 0, stream>>>(zcat, wsv, vcat);

    transpose_v<<<dim3(32, 32, 4), dim3(256), 0, stream>>>(vcat, vt);
    gemm_scores<<<dim3(16, 16, 4), dim3(256), 0, stream>>>(qcat, kcat, sc);
    softmax_kernel<<<dim3(NTOK), dim3(256), 0, stream>>>(sc);
    gemm_pv<<<dim3(16, 16, 4), dim3(256), 0, stream>>>((ushort_t*)sc, vt, outp);
}